// Round 6
// baseline (198.916 us; speedup 1.0000x reference)
//
#include <hip/hip_runtime.h>

// FAVOR+ causal linear attention — SINGLE plain dispatch, flag-based
// chunk-prefix (decoupled lookback, all blocks co-resident by construction).
// BH=8, D=DV=64, N=2048, M=128, chunk C=64, NC=32.
// Grid 512 = (half hb, bh, chunk c); 2 blocks/CU exactly (LDS 55KB, lb(256,2)).
//
// Phase A (m-half hb): phi-gen 3 orientations, St half + z half + swizzled
//   phi image halves -> global; fence; release flag[bh][c] (+1, reaches 2).
// Wait: acquire flags[bh][cc]==2 for cc<=c (publish-before-wait => no deadlock).
// Phase C (v-half hb): reload full phi images (32KB, L2/L3-warm), fp32
//   lookback-sum of predecessor St v-half rows -> S_excl in LDS, z lookback,
//   intra-causal GEMM + inter GEMM + norm + store.
// All LDS tiles XOR-swizzled: col ^= (row&7)<<3.

#define BH 8
#define D 64
#define DV 64
#define NSEQ 2048
#define M 128
#define CHK 64
#define NC (NSEQ / CHK)
#define PHI_SCALE 0.08838834764831845f  // 1/sqrt(128)

typedef unsigned int uint;
typedef unsigned short ushort;
typedef __attribute__((ext_vector_type(8))) short bf16x8;
typedef __attribute__((ext_vector_type(4))) short bf16x4;
typedef __attribute__((ext_vector_type(4))) float f32x4;
#define MFMA16(a, b, c) __builtin_amdgcn_mfma_f32_16x16x32_bf16((a), (b), (c), 0, 0, 0)

__device__ __forceinline__ short f2bf(float x) {  // RNE truncate fp32->bf16
    uint u = __float_as_uint(x);
    u += 0x7fffu + ((u >> 16) & 1u);
    return (short)(u >> 16);
}
__device__ __forceinline__ float bf2f(short b) {
    return __uint_as_float(((uint)(ushort)b) << 16);
}

// element-index XOR swizzles for bf16 tiles (rows of 64 / 128 elements)
#define SWZ64(r, c)  ((r) * 64  + ((c) ^ (((r) & 7) << 3)))
#define SWZ128(r, c) ((r) * 128 + ((c) ^ (((r) & 7) << 3)))

__global__ __launch_bounds__(256, 2) void favor_one(
    const float* __restrict__ keys, const float* __restrict__ values,
    const float* __restrict__ queries, const float* __restrict__ features,
    ushort* __restrict__ St, float* __restrict__ z,
    ushort* __restrict__ pQg, ushort* __restrict__ pKg,
    int* __restrict__ flags, float* __restrict__ out)
{
    const int hb = blockIdx.x >> 8, cid = blockIdx.x & 255;   // halves 256 apart
    const int bh = cid >> 5, c = cid & 31, n0 = c * CHK;
    const int tid = threadIdx.x;
    const int lane = tid & 63, wid = tid >> 6, quad = lane >> 4, l16 = lane & 15;

    __shared__ ulong2 smv[3440];                 // 55040 B -> 2 blocks/CU
    char* sm = (char*)smv;
    // phase A views
    short* sF    = (short*)sm;                   // @0     [64][64] F (m-half hb)
    short* sPKmn = (short*)(sm + 8192);          // @8192  [64][64] phiK[m_loc][n]
    short* sPQtH = (short*)(sm + 16384);         // @16384 [64][64] phiQ^T half
    short* sPKtH = (short*)(sm + 24576);         // @24576 [64][64] phiK^T half
    short* sV    = (short*)(sm + 32768);         // @32768 [32][64] V v-half (A->C)
    // phase C views (written only after the flag wait barrier)
    short* sPQ0  = (short*)sm;                   // @0     phiQ^T cols 0..63
    short* sPQ1  = (short*)(sm + 8192);          // @8192  phiQ^T cols 64..127
    short* sPK0  = (short*)(sm + 16384);         // @16384 phiK^T cols 0..63
    short* sPK1  = (short*)(sm + 24576);         // @24576 phiK^T cols 64..127
    short* sSx   = (short*)(sm + 36864);         // @36864 [32][128] S_excl SWZ128
    short* sAm   = (short*)(sm + 45056);         // @45056 [64][64] Amat SWZ64
    float* sNm   = (float*)(sm + 53248);         // [64] norm
    float* sNmP  = (float*)(sm + 53504);         // [64][4] norm-inter partials
    float* sZ    = (float*)(sm + 54528);         // [128] z_excl
    float* sOut  = (float*)sm;                   // [64][33] f32, post-B3 (aliases
                                                 //  sPQ0/1, dead by then)

    // ================= Phase A (m-half hb of chunk c) =================
    // F half-stage first, then K/Q reg loads, V A-frags + V v-half LDS stage
    for (int k = 0; k < 4; ++k) {
        const int i = tid + 256 * k;             // float4 idx within half (1024)
        float4 f = ((const float4*)features)[hb * 1024 + i];
        const int e = 4 * i, row = e >> 6, col = e & 63;
        bf16x4 bq;
        bq[0] = f2bf(f.x); bq[1] = f2bf(f.y); bq[2] = f2bf(f.z); bq[3] = f2bf(f.w);
        *(bf16x4*)(sF + SWZ64(row, col)) = bq;
    }
    const float* Kb = keys    + bh * D * NSEQ + n0 + 16 * wid + l16;
    const float* Qb = queries + bh * D * NSEQ + n0 + 16 * wid + l16;
    bf16x8 bK[2], aQ[2], aV[2];
    for (int h = 0; h < 2; ++h)
        for (int j = 0; j < 8; ++j) {
            const int d = 32 * h + 8 * quad + j;
            bK[h][j] = f2bf(Kb[d * NSEQ]);       // B-frag phiK[m][n], A-frag phiK^T
            aQ[h][j] = f2bf(Qb[d * NSEQ]);       // A-frag phiQ^T
        }
    {
        const float* Vb = values + bh * DV * NSEQ + n0;
        for (int h = 0; h < 2; ++h) {
            const float4* vp = (const float4*)(Vb + (16 * wid + l16) * NSEQ + 32 * h + 8 * quad);
            float4 v0 = vp[0], v1 = vp[1];
            aV[h][0] = f2bf(v0.x); aV[h][1] = f2bf(v0.y);
            aV[h][2] = f2bf(v0.z); aV[h][3] = f2bf(v0.w);
            aV[h][4] = f2bf(v1.x); aV[h][5] = f2bf(v1.y);
            aV[h][6] = f2bf(v1.z); aV[h][7] = f2bf(v1.w);
        }
    }
    {   // V v-half stage for phase C: row tid>>3 (32 rows), 8 cols each
        const int vrow = tid >> 3, cb2 = (tid & 7) * 8;
        const float4* vp = (const float4*)(values + (bh * DV + hb * 32 + vrow) * NSEQ
                                                  + n0 + cb2);
        float4 f0 = vp[0], f1 = vp[1];
        bf16x8 wv;
        wv[0] = f2bf(f0.x); wv[1] = f2bf(f0.y); wv[2] = f2bf(f0.z); wv[3] = f2bf(f0.w);
        wv[4] = f2bf(f1.x); wv[5] = f2bf(f1.y); wv[6] = f2bf(f1.z); wv[7] = f2bf(f1.w);
        *(bf16x8*)(sV + SWZ64(vrow, cb2)) = wv;
    }
    __syncthreads();  // B-A1: sF ready

    // phi generation for this m-half: one sF read feeds 3 MFMAs
    for (int mt = 0; mt < 4; ++mt) {
        f32x4 aMN = {0.f,0.f,0.f,0.f}, aQm = {0.f,0.f,0.f,0.f}, aKm = {0.f,0.f,0.f,0.f};
        for (int h = 0; h < 2; ++h) {
            bf16x8 fF = *(const bf16x8*)(sF + SWZ64(16 * mt + l16, 32 * h + 8 * quad));
            aMN = MFMA16(fF, bK[h], aMN);        // D[m][n] = F . K
            aQm = MFMA16(aQ[h], fF, aQm);        // D[n][m] = Q^T . F^T
            aKm = MFMA16(bK[h], fF, aKm);        // D[n][m] = K^T . F^T
        }
        for (int r = 0; r < 4; ++r) {
            const int mr = 16 * mt + 4 * quad + r;     // local m row
            sPKmn[SWZ64(mr, 16 * wid + l16)] = f2bf(fmaxf(aMN[r], 0.f) * PHI_SCALE);
            const int nr = 16 * wid + 4 * quad + r;    // row n
            sPQtH[SWZ64(nr, 16 * mt + l16)] = f2bf(fmaxf(aQm[r], 0.f) * PHI_SCALE);
            sPKtH[SWZ64(nr, 16 * mt + l16)] = f2bf(fmaxf(aKm[r], 0.f) * PHI_SCALE);
        }
    }
    __syncthreads();  // B-A2: phi tiles ready

    // z half (wave 0; other waves proceed to St MFMAs)
    if (tid < 64) {
        float s = 0.f;
        for (int n = 0; n < 64; ++n) s += bf2f(sPKmn[SWZ64(tid, (n + tid) & 63)]);
        z[(bh * NC + c) * M + hb * 64 + tid] = s;
    }
    // S^T[v][m-half] chunk-local -> global St
    {
        ushort* So = St + (size_t)(bh * NC + c) * (DV * M);
        for (int mt = 0; mt < 4; ++mt) {
            f32x4 acc = {0.f,0.f,0.f,0.f};
            for (int h = 0; h < 2; ++h) {
                bf16x8 bP = *(const bf16x8*)(sPKmn + SWZ64(16 * mt + l16, 32 * h + 8 * quad));
                acc = MFMA16(aV[h], bP, acc);
            }
            for (int r = 0; r < 4; ++r)
                So[(16 * wid + 4 * quad + r) * M + hb * 64 + 16 * mt + l16] =
                    (ushort)f2bf(acc[r]);
        }
    }
    // phi image halves -> global ([row][half][8 x ulong2] format)
    {
        ushort* pQc = pQg + (size_t)(bh * NC + c) * 8192;
        ushort* pKc = pKg + (size_t)(bh * NC + c) * 8192;
        const ulong2* sq = (const ulong2*)sPQtH;
        const ulong2* sk = (const ulong2*)sPKtH;
        for (int i = tid; i < 512; i += 256) {
            const int row = i >> 3, q = i & 7;
            ((ulong2*)pQc)[row * 16 + hb * 8 + q] = sq[i];
            ((ulong2*)pKc)[row * 16 + hb * 8 + q] = sk[i];
        }
    }

    // ---------------- publish, then wait (publish-first => no deadlock) ------
    __syncthreads();          // all stores issued & drained (vmcnt at barrier)
    __threadfence();          // agent-scope release of this block's writes
    if (tid == 0)
        __hip_atomic_fetch_add(&flags[bh * NC + c], 1,
                               __ATOMIC_RELEASE, __HIP_MEMORY_SCOPE_AGENT);
    for (int i = tid; i <= c; i += 256)   // need cc<c locals + own-chunk images
        while (__hip_atomic_load(&flags[bh * NC + i],
                                 __ATOMIC_ACQUIRE, __HIP_MEMORY_SCOPE_AGENT) < 2)
            __builtin_amdgcn_s_sleep(2);
    __syncthreads();
    __threadfence();          // acquire: invalidate stale cached lines
    // phase-A LDS (@0..32KB) now dead; safe to overwrite below

    // ================= Phase C (v-half hb of chunk c) =================
    // reload BOTH phi image halves (32KB, L2/L3-warm)
    {
        const ulong2* pQc = (const ulong2*)(pQg + (size_t)(bh * NC + c) * 8192);
        const ulong2* pKc = (const ulong2*)(pKg + (size_t)(bh * NC + c) * 8192);
        ulong2* dq = (ulong2*)sm;                // sPQ0 | sPQ1 (half-separated)
        ulong2* dk = (ulong2*)(sm + 16384);      // sPK0 | sPK1
        for (int i = tid; i < 1024; i += 256) {
            const int row = i >> 4, hh = (i >> 3) & 1, q = i & 7;
            dq[hh * 512 + row * 8 + q] = pQc[i];
            dk[hh * 512 + row * 8 + q] = pKc[i];
        }
    }
    // S_excl lookback: fp32 sum of predecessor St (v-half rows x full M)
    {
        float a0[8] = {0.f,0.f,0.f,0.f,0.f,0.f,0.f,0.f};
        float a1[8] = {0.f,0.f,0.f,0.f,0.f,0.f,0.f,0.f};
        const ushort* Sb = St + (size_t)bh * NC * 8192 + hb * 4096 + 16 * tid;
        for (int cc = 0; cc < c; ++cc) {
            bf16x8 v0 = *(const bf16x8*)(Sb + (size_t)cc * 8192);
            bf16x8 v1 = *(const bf16x8*)(Sb + (size_t)cc * 8192 + 8);
            #pragma unroll
            for (int j = 0; j < 8; ++j) { a0[j] += bf2f(v0[j]); a1[j] += bf2f(v1[j]); }
        }
        const int r = tid >> 3, cb = (16 * tid) & 127;
        bf16x8 w0, w1;
        #pragma unroll
        for (int j = 0; j < 8; ++j) { w0[j] = f2bf(a0[j]); w1[j] = f2bf(a1[j]); }
        *(bf16x8*)(sSx + SWZ128(r, cb))     = w0;
        *(bf16x8*)(sSx + SWZ128(r, cb + 8)) = w1;
    }
    // z_excl lookback
    if (tid < 128) {
        float s = 0.f;
        const float* zp = z + bh * NC * M + tid;
        for (int cc = 0; cc < c; ++cc) s += zp[cc * M];
        sZ[tid] = s;
    }
    __syncthreads();  // B-C1: sPQ*, sPK*, sSx, sV, sZ staged

    // C: Amat[n][j] = phiQ^T . phiK (masked), row-sums -> intra norm
    f32x4 accO[2], accC[4];
    accO[0] = (f32x4){0.f,0.f,0.f,0.f}; accO[1] = (f32x4){0.f,0.f,0.f,0.f};
    for (int t = 0; t < 4; ++t) accC[t] = (f32x4){0.f,0.f,0.f,0.f};
    for (int mt = 0; mt < 4; ++mt) {
        const short* qh = (mt < 2) ? sPQ0 : sPQ1;
        const short* kh = (mt < 2) ? sPK0 : sPK1;
        const int cb = 32 * (mt & 1) + 8 * quad;
        bf16x8 aP = *(const bf16x8*)(qh + SWZ64(16 * wid + l16, cb));
        for (int jt = 0; jt < 4; ++jt) {
            bf16x8 bK2 = *(const bf16x8*)(kh + SWZ64(16 * jt + l16, cb));
            accC[jt] = MFMA16(aP, bK2, accC[jt]);
        }
    }
    float rsum[4] = {0.f, 0.f, 0.f, 0.f};
    for (int jt = 0; jt < 4; ++jt)
        for (int r = 0; r < 4; ++r) {
            const int n = 16 * wid + 4 * quad + r;
            const int j = 16 * jt + l16;
            const float av = (j <= n) ? accC[jt][r] : 0.f;
            rsum[r] += av;
            sAm[SWZ64(n, j)] = f2bf(av);
        }
    for (int r = 0; r < 4; ++r) {
        float s = rsum[r];
        s += __shfl_xor(s, 1); s += __shfl_xor(s, 2);
        s += __shfl_xor(s, 4); s += __shfl_xor(s, 8);
        if (l16 == 0) sNm[16 * wid + 4 * quad + r] = s;  // intra part of norm
    }
    // inter: accO += phiQ^T . S_excl (B-frags from sSx)
    for (int mt = 0; mt < 4; ++mt) {
        const short* qh = (mt < 2) ? sPQ0 : sPQ1;
        const int cb = 32 * (mt & 1) + 8 * quad;
        bf16x8 aP = *(const bf16x8*)(qh + SWZ64(16 * wid + l16, cb));
        for (int vt = 0; vt < 2; ++vt) {
            bf16x8 bS = *(const bf16x8*)(sSx + SWZ128(16 * vt + l16, 32 * mt + 8 * quad));
            accO[vt] = MFMA16(aP, bS, accO[vt]);
        }
    }
    // norm inter part, wave-parallel: thread (n=tid&63, g=tid>>6) sums 32 m's
    {
        const int n = tid & 63, g = tid >> 6;
        const short* qh = (g < 2) ? sPQ0 : sPQ1;
        float s = 0.f;
        for (int mm = 0; mm < 32; ++mm) {
            const int m = 32 * g + ((mm + n) & 31);      // rotate: spread banks
            s += bf2f(qh[SWZ64(n, m & 63)]) * sZ[m];
        }
        sNmP[n * 4 + g] = s;
    }
    __syncthreads();  // B-C2: sAm, sNm(intra), sNmP ready; sPQ/sPK/sSx now dead

    // E: accO += Amat . V-half  (intra-chunk causal)
    for (int jh = 0; jh < 2; ++jh) {
        bf16x8 aA = *(const bf16x8*)(sAm + SWZ64(16 * wid + l16, 32 * jh + 8 * quad));
        for (int vt = 0; vt < 2; ++vt) {
            bf16x8 bV = *(const bf16x8*)(sV + SWZ64(16 * vt + l16, 32 * jh + 8 * quad));
            accO[vt] = MFMA16(aA, bV, accO[vt]);
        }
    }
    if (tid < 64)
        sNm[tid] += sNmP[tid * 4] + sNmP[tid * 4 + 1] + sNmP[tid * 4 + 2] + sNmP[tid * 4 + 3];
    __syncthreads();  // B-C3: sNm final; sOut alias (@0) safe

    for (int vt = 0; vt < 2; ++vt)
        for (int r = 0; r < 4; ++r) {
            const int n = 16 * wid + 4 * quad + r, vl = 16 * vt + l16;
            sOut[n * 33 + vl] = accO[vt][r] / sNm[n];
        }
    __syncthreads();  // B-C4
    for (int i = tid; i < 2048; i += 256) {
        const int vl = i >> 6, n = i & 63;
        out[(bh * DV + hb * 32 + vl) * NSEQ + n0 + n] = sOut[n * 33 + vl];
    }
}

extern "C" void kernel_launch(void* const* d_in, const int* in_sizes, int n_in,
                              void* d_out, int out_size, void* d_ws, size_t ws_size,
                              hipStream_t stream)
{
    (void)in_sizes; (void)n_in; (void)out_size; (void)ws_size;
    const float* keys     = (const float*)d_in[0];
    const float* values   = (const float*)d_in[1];
    const float* queries  = (const float*)d_in[2];
    const float* features = (const float*)d_in[3];
    float* outp = (float*)d_out;

    // ws: St bf16 (4 MB) | z f32 (128 KB) | pQ images (4 MB) | pK images (4 MB)
    //   | flags int[256] (1 KB)
    char* w = (char*)d_ws;
    ushort* St   = (ushort*)w;
    float*  z    = (float*)(w + (size_t)4 * 1024 * 1024);
    ushort* pQg  = (ushort*)(w + (size_t)4 * 1024 * 1024 + 128 * 1024);
    ushort* pKg  = (ushort*)(w + (size_t)8 * 1024 * 1024 + 128 * 1024);
    int*   flags = (int*)  (w + (size_t)12 * 1024 * 1024 + 128 * 1024);

    hipMemsetAsync(flags, 0, BH * NC * sizeof(int), stream);
    favor_one<<<dim3(512), dim3(256), 0, stream>>>(keys, values, queries, features,
                                                   St, z, pQg, pKg, flags, outp);
}

// Round 8
// 148.142 us; speedup vs baseline: 1.3427x; 1.3427x over previous
//
#include <hip/hip_runtime.h>

// FAVOR+ causal linear attention — SINGLE plain dispatch, two flag edges.
// BH=8, D=DV=64, N=2048, M=128, chunk C=64, NC=32.
// Grid 512 = (half hb, bh, chunk c); 2 blocks/CU exactly (LDS 55KB, lb(256,2)).
//
// Phase A (m-half hb): phi-gen 3 orientations, St half + z half + swizzled
//   phi image halves -> global; release-publish flag1[bh][c] (+1 -> 2).
// Edge 1: RELAXED polls of flag1 (no per-poll invalidate!) + one acquire fence.
// Scan (block b -> (sbh=b>>6, sv=b&63)): balanced parallel exclusive prefix
//   over chunks for St row sv (128 cols, half-split 16+16 with LDS carry) and
//   2 z columns -> separate Sx / zx buffers; release-publish flag2[b].
// Edge 2: RELAXED polls of the 64 flag2's for this bh + one acquire fence.
// Phase C (v-half hb): S_excl B-frags hoisted to regs from Sx, phi images
//   reloaded (L2-warm), intra-causal GEMM + inter GEMM + norm + store.
// All LDS tiles XOR-swizzled: col ^= (row&7)<<3.

#define BH 8
#define D 64
#define DV 64
#define NSEQ 2048
#define M 128
#define CHK 64
#define NC (NSEQ / CHK)
#define PHI_SCALE 0.08838834764831845f  // 1/sqrt(128)

typedef unsigned int uint;
typedef unsigned short ushort;
typedef __attribute__((ext_vector_type(8))) short bf16x8;
typedef __attribute__((ext_vector_type(4))) short bf16x4;
typedef __attribute__((ext_vector_type(4))) float f32x4;
#define MFMA16(a, b, c) __builtin_amdgcn_mfma_f32_16x16x32_bf16((a), (b), (c), 0, 0, 0)

__device__ __forceinline__ short f2bf(float x) {  // RNE truncate fp32->bf16
    uint u = __float_as_uint(x);
    u += 0x7fffu + ((u >> 16) & 1u);
    return (short)(u >> 16);
}
__device__ __forceinline__ float bf2f(short b) {
    return __uint_as_float(((uint)(ushort)b) << 16);
}

// element-index XOR swizzles for bf16 tiles (rows of 64 / 128 elements)
#define SWZ64(r, c)  ((r) * 64  + ((c) ^ (((r) & 7) << 3)))
#define SWZ128(r, c) ((r) * 128 + ((c) ^ (((r) & 7) << 3)))

__global__ __launch_bounds__(256, 2) void favor_one(
    const float* __restrict__ keys, const float* __restrict__ values,
    const float* __restrict__ queries, const float* __restrict__ features,
    ushort* __restrict__ St, float* __restrict__ z,
    ushort* __restrict__ pQg, ushort* __restrict__ pKg,
    ushort* __restrict__ Sx, float* __restrict__ zx,
    int* __restrict__ flag1, int* __restrict__ flag2,
    float* __restrict__ out)
{
    const int b = blockIdx.x;
    const int hb = b >> 8, cid = b & 255;          // A/C roles
    const int bh = cid >> 5, c = cid & 31, n0 = c * CHK;
    const int sbh = b >> 6, sv = b & 63;           // scan role
    const int tid = threadIdx.x;
    const int lane = tid & 63, wid = tid >> 6, quad = lane >> 4, l16 = lane & 15;

    __shared__ ulong2 smv[3440];                 // 55040 B -> 2 blocks/CU
    char* sm = (char*)smv;
    // phase A views
    short* sF    = (short*)sm;                   // @0     [64][64] F (m-half hb)
    short* sPKmn = (short*)(sm + 8192);          // @8192  [64][64] phiK[m_loc][n]
    short* sPQtH = (short*)(sm + 16384);         // @16384 [64][64] phiQ^T half
    short* sPKtH = (short*)(sm + 24576);         // @24576 [64][64] phiK^T half
    short* sV    = (short*)(sm + 32768);         // @32768 [32][64] V v-half (A->C)
    // scan view (dead before phase C's sNm use)
    float* sCar  = (float*)(sm + 53248);         // [128] scan carry
    // phase C views (written only after edge 2)
    short* sPQ0  = (short*)sm;                   // @0     phiQ^T cols 0..63
    short* sPQ1  = (short*)(sm + 8192);          // @8192  phiQ^T cols 64..127
    short* sPK0  = (short*)(sm + 16384);         // @16384 phiK^T cols 0..63
    short* sPK1  = (short*)(sm + 24576);         // @24576 phiK^T cols 64..127
    short* sAm   = (short*)(sm + 45056);         // @45056 [64][64] Amat SWZ64
    float* sNm   = (float*)(sm + 53248);         // [64] norm (carry dead)
    float* sNmP  = (float*)(sm + 53504);         // [64][4] norm-inter partials
    float* sZ    = (float*)(sm + 54528);         // [128] z_excl
    float* sOut  = (float*)sm;                   // [64][33] f32, post-C2 (aliases
                                                 //  sPQ0/1, dead by then)

    // ================= Phase A (m-half hb of chunk c) =================
    for (int k = 0; k < 4; ++k) {
        const int i = tid + 256 * k;             // float4 idx within half (1024)
        float4 f = ((const float4*)features)[hb * 1024 + i];
        const int e = 4 * i, row = e >> 6, col = e & 63;
        bf16x4 bq;
        bq[0] = f2bf(f.x); bq[1] = f2bf(f.y); bq[2] = f2bf(f.z); bq[3] = f2bf(f.w);
        *(bf16x4*)(sF + SWZ64(row, col)) = bq;
    }
    const float* Kb = keys    + bh * D * NSEQ + n0 + 16 * wid + l16;
    const float* Qb = queries + bh * D * NSEQ + n0 + 16 * wid + l16;
    bf16x8 bK[2], aQ[2], aV[2];
    for (int h = 0; h < 2; ++h)
        for (int j = 0; j < 8; ++j) {
            const int d = 32 * h + 8 * quad + j;
            bK[h][j] = f2bf(Kb[d * NSEQ]);       // B-frag phiK[m][n], A-frag phiK^T
            aQ[h][j] = f2bf(Qb[d * NSEQ]);       // A-frag phiQ^T
        }
    {
        const float* Vb = values + bh * DV * NSEQ + n0;
        for (int h = 0; h < 2; ++h) {
            const float4* vp = (const float4*)(Vb + (16 * wid + l16) * NSEQ + 32 * h + 8 * quad);
            float4 v0 = vp[0], v1 = vp[1];
            aV[h][0] = f2bf(v0.x); aV[h][1] = f2bf(v0.y);
            aV[h][2] = f2bf(v0.z); aV[h][3] = f2bf(v0.w);
            aV[h][4] = f2bf(v1.x); aV[h][5] = f2bf(v1.y);
            aV[h][6] = f2bf(v1.z); aV[h][7] = f2bf(v1.w);
        }
    }
    {   // V v-half stage for phase C: row tid>>3 (32 rows), 8 cols each
        const int vrow = tid >> 3, cb2 = (tid & 7) * 8;
        const float4* vp = (const float4*)(values + (bh * DV + hb * 32 + vrow) * NSEQ
                                                  + n0 + cb2);
        float4 f0 = vp[0], f1 = vp[1];
        bf16x8 wv;
        wv[0] = f2bf(f0.x); wv[1] = f2bf(f0.y); wv[2] = f2bf(f0.z); wv[3] = f2bf(f0.w);
        wv[4] = f2bf(f1.x); wv[5] = f2bf(f1.y); wv[6] = f2bf(f1.z); wv[7] = f2bf(f1.w);
        *(bf16x8*)(sV + SWZ64(vrow, cb2)) = wv;
    }
    __syncthreads();  // B-A1: sF ready

    for (int mt = 0; mt < 4; ++mt) {
        f32x4 aMN = {0.f,0.f,0.f,0.f}, aQm = {0.f,0.f,0.f,0.f}, aKm = {0.f,0.f,0.f,0.f};
        for (int h = 0; h < 2; ++h) {
            bf16x8 fF = *(const bf16x8*)(sF + SWZ64(16 * mt + l16, 32 * h + 8 * quad));
            aMN = MFMA16(fF, bK[h], aMN);        // D[m][n] = F . K
            aQm = MFMA16(aQ[h], fF, aQm);        // D[n][m] = Q^T . F^T
            aKm = MFMA16(bK[h], fF, aKm);        // D[n][m] = K^T . F^T
        }
        for (int r = 0; r < 4; ++r) {
            const int mr = 16 * mt + 4 * quad + r;     // local m row
            sPKmn[SWZ64(mr, 16 * wid + l16)] = f2bf(fmaxf(aMN[r], 0.f) * PHI_SCALE);
            const int nr = 16 * wid + 4 * quad + r;    // row n
            sPQtH[SWZ64(nr, 16 * mt + l16)] = f2bf(fmaxf(aQm[r], 0.f) * PHI_SCALE);
            sPKtH[SWZ64(nr, 16 * mt + l16)] = f2bf(fmaxf(aKm[r], 0.f) * PHI_SCALE);
        }
    }
    __syncthreads();  // B-A2: phi tiles ready

    if (tid < 64) {   // z half
        float s = 0.f;
        for (int n = 0; n < 64; ++n) s += bf2f(sPKmn[SWZ64(tid, (n + tid) & 63)]);
        z[(bh * NC + c) * M + hb * 64 + tid] = s;
    }
    {   // S^T[v][m-half] chunk-local -> global St
        ushort* So = St + (size_t)(bh * NC + c) * (DV * M);
        for (int mt = 0; mt < 4; ++mt) {
            f32x4 acc = {0.f,0.f,0.f,0.f};
            for (int h = 0; h < 2; ++h) {
                bf16x8 bP = *(const bf16x8*)(sPKmn + SWZ64(16 * mt + l16, 32 * h + 8 * quad));
                acc = MFMA16(aV[h], bP, acc);
            }
            for (int r = 0; r < 4; ++r)
                So[(16 * wid + 4 * quad + r) * M + hb * 64 + 16 * mt + l16] =
                    (ushort)f2bf(acc[r]);
        }
    }
    {   // phi image halves -> global ([row][half][8 x ulong2] format)
        ushort* pQc = pQg + (size_t)(bh * NC + c) * 8192;
        ushort* pKc = pKg + (size_t)(bh * NC + c) * 8192;
        const ulong2* sq = (const ulong2*)sPQtH;
        const ulong2* sk = (const ulong2*)sPKtH;
        for (int i = tid; i < 512; i += 256) {
            const int row = i >> 3, q = i & 7;
            ((ulong2*)pQc)[row * 16 + hb * 8 + q] = sq[i];
            ((ulong2*)pKc)[row * 16 + hb * 8 + q] = sk[i];
        }
    }

    // ---- publish A (release add does the wbl2), then edge 1: relaxed polls ----
    __syncthreads();          // all waves' stores drained (vmcnt at barrier)
    if (tid == 0)
        __hip_atomic_fetch_add(&flag1[bh * NC + c], 1,
                               __ATOMIC_RELEASE, __HIP_MEMORY_SCOPE_AGENT);
    if (tid < 32)             // scan needs all chunks of sbh (both halves: ==2)
        while (__hip_atomic_load(&flag1[sbh * NC + tid],
                                 __ATOMIC_RELAXED, __HIP_MEMORY_SCOPE_AGENT) < 2)
            __builtin_amdgcn_s_sleep(1);
    __syncthreads();
    __builtin_amdgcn_fence(__ATOMIC_ACQUIRE, "agent");   // one inv per block

    // ================= Scan (row sv of sbh): balanced exclusive prefix ========
    {
        const int m = tid & 127, half = tid >> 7;
        const ushort* ps = St + (size_t)sbh * NC * 8192 + sv * 128 + m;
        ushort*       pd = Sx + (size_t)sbh * NC * 8192 + sv * 128 + m;
        float vals[16];
        #pragma unroll
        for (int k = 0; k < 16; ++k) vals[k] = bf2f(ps[(size_t)(16 * half + k) * 8192]);
        if (half == 0) {
            float total = 0.f;
            #pragma unroll
            for (int k = 0; k < 16; ++k) total += vals[k];
            sCar[m] = total;
        }
        __syncthreads();
        float run = half ? sCar[m] : 0.f;
        #pragma unroll
        for (int k = 0; k < 16; ++k) {
            pd[(size_t)(16 * half + k) * 8192] = (ushort)f2bf(run);
            run += vals[k];
        }
        if (tid < 2) {                           // 2 z columns per block
            const int mz = 2 * sv + tid;
            const float* zs = z  + sbh * NC * M + mz;
            float*       zd = zx + sbh * NC * M + mz;
            float zv[NC];
            #pragma unroll
            for (int cc = 0; cc < NC; ++cc) zv[cc] = zs[cc * M];
            float zr = 0.f;
            #pragma unroll
            for (int cc = 0; cc < NC; ++cc) { zd[cc * M] = zr; zr += zv[cc]; }
        }
    }
    // ---- publish scan, edge 2: relaxed polls of this bh's 64 scan blocks ----
    __syncthreads();
    if (tid == 0)
        __hip_atomic_fetch_add(&flag2[b], 1,
                               __ATOMIC_RELEASE, __HIP_MEMORY_SCOPE_AGENT);
    if (tid < 64)
        while (__hip_atomic_load(&flag2[bh * 64 + tid],
                                 __ATOMIC_RELAXED, __HIP_MEMORY_SCOPE_AGENT) < 1)
            __builtin_amdgcn_s_sleep(1);
    __syncthreads();
    __builtin_amdgcn_fence(__ATOMIC_ACQUIRE, "agent");
    // phase-A LDS (@0..32KB) dead; carry dead; safe to overwrite below

    // ================= Phase C (v-half hb of chunk c) =================
    // hoist S_excl B-frags to regs first (latency hides under image staging)
    bf16x8 bS[4][2];
    {
        const ushort* Sb = Sx + (size_t)(bh * NC + c) * 8192;
        #pragma unroll
        for (int mt = 0; mt < 4; ++mt)
            #pragma unroll
            for (int vt = 0; vt < 2; ++vt)
                bS[mt][vt] = *(const bf16x8*)(Sb + (hb * 32 + 16 * vt + l16) * 128
                                                 + 32 * mt + 8 * quad);
    }
    {   // reload BOTH phi image halves (32KB, L2/L3-warm)
        const ulong2* pQc = (const ulong2*)(pQg + (size_t)(bh * NC + c) * 8192);
        const ulong2* pKc = (const ulong2*)(pKg + (size_t)(bh * NC + c) * 8192);
        ulong2* dq = (ulong2*)sm;                // sPQ0 | sPQ1 (half-separated)
        ulong2* dk = (ulong2*)(sm + 16384);      // sPK0 | sPK1
        for (int i = tid; i < 1024; i += 256) {
            const int row = i >> 4, hh = (i >> 3) & 1, q = i & 7;
            dq[hh * 512 + row * 8 + q] = pQc[i];
            dk[hh * 512 + row * 8 + q] = pKc[i];
        }
    }
    if (tid < 128) sZ[tid] = zx[(bh * NC + c) * M + tid];
    __syncthreads();  // B-C1: sPQ*, sPK*, sZ staged (sV from phase A)

    f32x4 accO[2], accC[4];
    accO[0] = (f32x4){0.f,0.f,0.f,0.f}; accO[1] = (f32x4){0.f,0.f,0.f,0.f};
    for (int t = 0; t < 4; ++t) accC[t] = (f32x4){0.f,0.f,0.f,0.f};
    for (int mt = 0; mt < 4; ++mt) {
        const short* qh = (mt < 2) ? sPQ0 : sPQ1;
        const short* kh = (mt < 2) ? sPK0 : sPK1;
        const int cb = 32 * (mt & 1) + 8 * quad;
        bf16x8 aP = *(const bf16x8*)(qh + SWZ64(16 * wid + l16, cb));
        for (int jt = 0; jt < 4; ++jt) {
            bf16x8 bK2 = *(const bf16x8*)(kh + SWZ64(16 * jt + l16, cb));
            accC[jt] = MFMA16(aP, bK2, accC[jt]);
        }
    }
    float rsum[4] = {0.f, 0.f, 0.f, 0.f};
    for (int jt = 0; jt < 4; ++jt)
        for (int r = 0; r < 4; ++r) {
            const int n = 16 * wid + 4 * quad + r;
            const int j = 16 * jt + l16;
            const float av = (j <= n) ? accC[jt][r] : 0.f;
            rsum[r] += av;
            sAm[SWZ64(n, j)] = f2bf(av);
        }
    for (int r = 0; r < 4; ++r) {
        float s = rsum[r];
        s += __shfl_xor(s, 1); s += __shfl_xor(s, 2);
        s += __shfl_xor(s, 4); s += __shfl_xor(s, 8);
        if (l16 == 0) sNm[16 * wid + 4 * quad + r] = s;  // intra part of norm
    }
    // inter: accO += phiQ^T . S_excl (B-frags in registers)
    for (int mt = 0; mt < 4; ++mt) {
        const short* qh = (mt < 2) ? sPQ0 : sPQ1;
        const int cb = 32 * (mt & 1) + 8 * quad;
        bf16x8 aP = *(const bf16x8*)(qh + SWZ64(16 * wid + l16, cb));
        for (int vt = 0; vt < 2; ++vt)
            accO[vt] = MFMA16(aP, bS[mt][vt], accO[vt]);
    }
    // norm inter part, wave-parallel
    {
        const int n = tid & 63, g = tid >> 6;
        const short* qh = (g < 2) ? sPQ0 : sPQ1;
        float s = 0.f;
        for (int mm = 0; mm < 32; ++mm) {
            const int m = 32 * g + ((mm + n) & 31);      // rotate: spread banks
            s += bf2f(qh[SWZ64(n, m & 63)]) * sZ[m];
        }
        sNmP[n * 4 + g] = s;
    }
    __syncthreads();  // B-C2: sAm, sNm(intra), sNmP ready; sPQ/sPK now dead

    for (int jh = 0; jh < 2; ++jh) {   // E: accO += Amat . V-half
        bf16x8 aA = *(const bf16x8*)(sAm + SWZ64(16 * wid + l16, 32 * jh + 8 * quad));
        for (int vt = 0; vt < 2; ++vt) {
            bf16x8 bV = *(const bf16x8*)(sV + SWZ64(16 * vt + l16, 32 * jh + 8 * quad));
            accO[vt] = MFMA16(aA, bV, accO[vt]);
        }
    }
    if (tid < 64)
        sNm[tid] += sNmP[tid * 4] + sNmP[tid * 4 + 1] + sNmP[tid * 4 + 2] + sNmP[tid * 4 + 3];
    __syncthreads();  // B-C3: sNm final; sOut alias (@0) safe

    for (int vt = 0; vt < 2; ++vt)
        for (int r = 0; r < 4; ++r) {
            const int n = 16 * wid + 4 * quad + r, vl = 16 * vt + l16;
            sOut[n * 33 + vl] = accO[vt][r] / sNm[n];
        }
    __syncthreads();  // B-C4
    for (int i = tid; i < 2048; i += 256) {
        const int vl = i >> 6, n = i & 63;
        out[(bh * DV + hb * 32 + vl) * NSEQ + n0 + n] = sOut[n * 33 + vl];
    }
}

extern "C" void kernel_launch(void* const* d_in, const int* in_sizes, int n_in,
                              void* d_out, int out_size, void* d_ws, size_t ws_size,
                              hipStream_t stream)
{
    (void)in_sizes; (void)n_in; (void)out_size; (void)ws_size;
    const float* keys     = (const float*)d_in[0];
    const float* values   = (const float*)d_in[1];
    const float* queries  = (const float*)d_in[2];
    const float* features = (const float*)d_in[3];
    float* outp = (float*)d_out;

    // ws: St (4MB) | z (128KB) | pQ (4MB) | pK (4MB) | Sx (4MB) | zx (128KB)
    //   | flag1[256] + flag2[512]
    char* w = (char*)d_ws;
    const size_t MB = 1024 * 1024;
    ushort* St   = (ushort*)w;
    float*  z    = (float*)(w + 4 * MB);
    ushort* pQg  = (ushort*)(w + 4 * MB + 128 * 1024);
    ushort* pKg  = (ushort*)(w + 8 * MB + 128 * 1024);
    ushort* Sx   = (ushort*)(w + 12 * MB + 128 * 1024);
    float*  zx   = (float*)(w + 16 * MB + 128 * 1024);
    int*   flag1 = (int*)  (w + 16 * MB + 256 * 1024);
    int*   flag2 = flag1 + 256;

    hipMemsetAsync(flag1, 0, (256 + 512) * sizeof(int), stream);
    favor_one<<<dim3(512), dim3(256), 0, stream>>>(keys, values, queries, features,
                                                   St, z, pQg, pKg, Sx, zx,
                                                   flag1, flag2, outp);
}

// Round 9
// 95.321 us; speedup vs baseline: 2.0868x; 1.5541x over previous
//
#include <hip/hip_runtime.h>

// FAVOR+ causal linear attention — 2-dispatch chunk-parallel pipeline.
// BH=8, D=DV=64, N=2048, M=128, chunk C=64, NC=32. Grids 512 = 2 blocks/CU.
//
// K1 (per chunk, m-half hb): phi-gen (3 orientations from one F-frag read),
//   chunk-local S^T column-half + z half + swizzled phi image halves -> global.
// K2 (per chunk, v-half hb): phi images -> LDS (coalesced, L2-warm),
//   per-block fp32 lookback over the <=31 predecessor St v-half slices
//   (62 coalesced 16B loads/thread worst case, no scan dispatch), z lookback,
//   intra-causal GEMM + inter GEMM + norm + store.
// All LDS tiles XOR-swizzled: col ^= (row&7)<<3.
// (Single-dispatch w/ flag edges measured WORSE: 83-144us vs ~45us kernel-side
//  across R2/R6/R8 — global in-kernel phase edges cost more than dispatches.)

#define BH 8
#define D 64
#define DV 64
#define NSEQ 2048
#define M 128
#define CHK 64
#define NC (NSEQ / CHK)
#define PHI_SCALE 0.08838834764831845f  // 1/sqrt(128)

typedef unsigned int uint;
typedef unsigned short ushort;
typedef __attribute__((ext_vector_type(8))) short bf16x8;
typedef __attribute__((ext_vector_type(4))) short bf16x4;
typedef __attribute__((ext_vector_type(4))) float f32x4;
#define MFMA16(a, b, c) __builtin_amdgcn_mfma_f32_16x16x32_bf16((a), (b), (c), 0, 0, 0)

__device__ __forceinline__ short f2bf(float x) {  // RNE truncate fp32->bf16
    uint u = __float_as_uint(x);
    u += 0x7fffu + ((u >> 16) & 1u);
    return (short)(u >> 16);
}
__device__ __forceinline__ float bf2f(short b) {
    return __uint_as_float(((uint)(ushort)b) << 16);
}

// element-index XOR swizzles for bf16 tiles (rows of 64 / 128 elements)
#define SWZ64(r, c)  ((r) * 64  + ((c) ^ (((r) & 7) << 3)))
#define SWZ128(r, c) ((r) * 128 + ((c) ^ (((r) & 7) << 3)))

// ---------------- Kernel 1: 512 blocks = (m-half, chunk) ----------------
__global__ __launch_bounds__(256, 2) void favor_p1(
    const float* __restrict__ keys, const float* __restrict__ values,
    const float* __restrict__ queries, const float* __restrict__ features,
    ushort* __restrict__ St, float* __restrict__ z,
    ushort* __restrict__ pQg, ushort* __restrict__ pKg)
{
    const int mh = blockIdx.x >> 8, cid = blockIdx.x & 255;   // halves 256 apart
    const int bh = cid >> 5, c = cid & 31, n0 = c * CHK;
    const int tid = threadIdx.x;
    const int lane = tid & 63, wid = tid >> 6, quad = lane >> 4, l16 = lane & 15;

    __shared__ ulong2 smv[2048];               // 32 KB -> 2 blocks/CU
    short* sF    = (short*)smv;                // [64][64] bf16 F (this m-half)
    short* sPKmn = (short*)smv + 4096;         // [64][64] bf16 phiK[m_loc][n]
    short* sPQt  = (short*)smv + 8192;         // [64][64] bf16 phiQ^T cols m-half
    short* sPKt  = (short*)smv + 12288;        // [64][64] bf16 phiK^T cols m-half

    // F half-stage first (feeds the first barrier), then K/Q/V reg loads
    for (int k = 0; k < 4; ++k) {
        const int i = tid + 256 * k;           // float4 idx within half (1024)
        float4 f = ((const float4*)features)[mh * 1024 + i];
        const int e = 4 * i, row = e >> 6, col = e & 63;
        bf16x4 bq;
        bq[0] = f2bf(f.x); bq[1] = f2bf(f.y); bq[2] = f2bf(f.z); bq[3] = f2bf(f.w);
        *(bf16x4*)(sF + SWZ64(row, col)) = bq;
    }
    const float* Kb = keys    + bh * D * NSEQ + n0 + 16 * wid + l16;
    const float* Qb = queries + bh * D * NSEQ + n0 + 16 * wid + l16;
    bf16x8 bK[2], aQ[2], aV[2];
    for (int h = 0; h < 2; ++h)
        for (int j = 0; j < 8; ++j) {
            const int d = 32 * h + 8 * quad + j;
            bK[h][j] = f2bf(Kb[d * NSEQ]);     // B-frag phiK[m][n], A-frag phiK^T
            aQ[h][j] = f2bf(Qb[d * NSEQ]);     // A-frag phiQ^T
        }
    {
        const float* Vb = values + bh * DV * NSEQ + n0;
        for (int h = 0; h < 2; ++h) {
            const float4* vp = (const float4*)(Vb + (16 * wid + l16) * NSEQ + 32 * h + 8 * quad);
            float4 v0 = vp[0], v1 = vp[1];
            aV[h][0] = f2bf(v0.x); aV[h][1] = f2bf(v0.y);
            aV[h][2] = f2bf(v0.z); aV[h][3] = f2bf(v0.w);
            aV[h][4] = f2bf(v1.x); aV[h][5] = f2bf(v1.y);
            aV[h][6] = f2bf(v1.z); aV[h][7] = f2bf(v1.w);
        }
    }
    __syncthreads();  // B1: sF ready

    // phi generation for this m-half: one sF read feeds 3 MFMAs
    for (int mt = 0; mt < 4; ++mt) {
        f32x4 aMN = {0.f,0.f,0.f,0.f}, aQm = {0.f,0.f,0.f,0.f}, aKm = {0.f,0.f,0.f,0.f};
        for (int h = 0; h < 2; ++h) {
            bf16x8 fF = *(const bf16x8*)(sF + SWZ64(16 * mt + l16, 32 * h + 8 * quad));
            aMN = MFMA16(fF, bK[h], aMN);      // D[m][n] = F . K
            aQm = MFMA16(aQ[h], fF, aQm);      // D[n][m] = Q^T . F^T
            aKm = MFMA16(bK[h], fF, aKm);      // D[n][m] = K^T . F^T
        }
        for (int r = 0; r < 4; ++r) {
            const int mr = 16 * mt + 4 * quad + r;     // local m row
            sPKmn[SWZ64(mr, 16 * wid + l16)] = f2bf(fmaxf(aMN[r], 0.f) * PHI_SCALE);
            const int nr = 16 * wid + 4 * quad + r;    // row n
            sPQt[SWZ64(nr, 16 * mt + l16)] = f2bf(fmaxf(aQm[r], 0.f) * PHI_SCALE);
            sPKt[SWZ64(nr, 16 * mt + l16)] = f2bf(fmaxf(aKm[r], 0.f) * PHI_SCALE);
        }
    }
    __syncthreads();  // B2: phi tiles ready

    // z half (wave 0 only; waves 1-3 proceed to St MFMAs)
    if (tid < 64) {
        float s = 0.f;
        for (int n = 0; n < 64; ++n) s += bf2f(sPKmn[SWZ64(tid, (n + tid) & 63)]);
        z[(bh * NC + c) * M + mh * 64 + tid] = s;
    }

    // S^T[v][m-half] chunk-local -> global St
    {
        ushort* So = St + (size_t)(bh * NC + c) * (DV * M);
        for (int mt = 0; mt < 4; ++mt) {
            f32x4 acc = {0.f,0.f,0.f,0.f};
            for (int h = 0; h < 2; ++h) {
                bf16x8 bP = *(const bf16x8*)(sPKmn + SWZ64(16 * mt + l16, 32 * h + 8 * quad));
                acc = MFMA16(aV[h], bP, acc);
            }
            for (int r = 0; r < 4; ++r)
                So[(16 * wid + 4 * quad + r) * M + mh * 64 + 16 * mt + l16] =
                    (ushort)f2bf(acc[r]);
        }
    }

    // phi image halves -> global ([row][half][8 x ulong2] format, coalesced)
    {
        ushort* pQc = pQg + (size_t)(bh * NC + c) * 8192;
        ushort* pKc = pKg + (size_t)(bh * NC + c) * 8192;
        const ulong2* sq = (const ulong2*)sPQt;
        const ulong2* sk = (const ulong2*)sPKt;
        for (int i = tid; i < 512; i += 256) {
            const int row = i >> 3, q = i & 7;
            ((ulong2*)pQc)[row * 16 + mh * 8 + q] = sq[i];
            ((ulong2*)pKc)[row * 16 + mh * 8 + q] = sk[i];
        }
    }
}

// ---------------- Kernel 2: 512 blocks = (v-half, chunk), lookback folded ---
__global__ __launch_bounds__(256, 2) void favor_p2k(
    const float* __restrict__ values, const ushort* __restrict__ St,
    const float* __restrict__ z, const ushort* __restrict__ pQg,
    const ushort* __restrict__ pKg, float* __restrict__ out)
{
    const int hb = blockIdx.x >> 8, cid = blockIdx.x & 255;
    const int bh = cid >> 5, c = cid & 31, n0 = c * CHK;
    const int tid = threadIdx.x;
    const int lane = tid & 63, wid = tid >> 6, quad = lane >> 4, l16 = lane & 15;

    __shared__ ulong2 smv[3440];                 // 55040 B -> 2 blocks/CU
    char* sm = (char*)smv;
    short* sPQ0  = (short*)sm;                   // @0     phiQ^T cols 0..63
    short* sPQ1  = (short*)(sm + 8192);          // @8192  phiQ^T cols 64..127
    short* sPK0  = (short*)(sm + 16384);         // @16384 phiK^T cols 0..63
    short* sPK1  = (short*)(sm + 24576);         // @24576 phiK^T cols 64..127
    short* sV    = (short*)(sm + 32768);         // @32768 [32][64] V v-half
    short* sSx   = (short*)(sm + 36864);         // @36864 [32][128] S_excl SWZ128
    short* sAm   = (short*)(sm + 45056);         // @45056 [64][64] Amat SWZ64
    float* sNm   = (float*)(sm + 53248);         // [64] norm
    float* sNmP  = (float*)(sm + 53504);         // [64][4] norm-inter partials
    float* sZ    = (float*)(sm + 54528);         // [128] z_excl
    float* sOut  = (float*)sm;                   // [64][33] f32, post-C2 (aliases
                                                 //  sPQ0/1, dead by then)

    // phi images global->LDS (coalesced 16B/lane; half-separated buffers)
    {
        const ulong2* pQc = (const ulong2*)(pQg + (size_t)(bh * NC + c) * 8192);
        const ulong2* pKc = (const ulong2*)(pKg + (size_t)(bh * NC + c) * 8192);
        ulong2* dq = (ulong2*)sm;                // sPQ0 | sPQ1
        ulong2* dk = (ulong2*)(sm + 16384);      // sPK0 | sPK1
        for (int i = tid; i < 1024; i += 256) {
            const int row = i >> 4, hh = (i >> 3) & 1, q = i & 7;
            dq[hh * 512 + row * 8 + q] = pQc[i];
            dk[hh * 512 + row * 8 + q] = pKc[i];
        }
    }
    {   // V v-half stage: row tid>>3 (32 rows), 8 cols each
        const int vrow = tid >> 3, cb2 = (tid & 7) * 8;
        const float4* vp = (const float4*)(values + (bh * DV + hb * 32 + vrow) * NSEQ
                                                  + n0 + cb2);
        float4 f0 = vp[0], f1 = vp[1];
        bf16x8 wv;
        wv[0] = f2bf(f0.x); wv[1] = f2bf(f0.y); wv[2] = f2bf(f0.z); wv[3] = f2bf(f0.w);
        wv[4] = f2bf(f1.x); wv[5] = f2bf(f1.y); wv[6] = f2bf(f1.z); wv[7] = f2bf(f1.w);
        *(bf16x8*)(sV + SWZ64(vrow, cb2)) = wv;
    }
    // S_excl lookback: fp32 sum of predecessor St v-half slices (coalesced:
    // wave reads 1KB runs per chunk; <=62 independent 16B loads/thread)
    {
        float a0[8] = {0.f,0.f,0.f,0.f,0.f,0.f,0.f,0.f};
        float a1[8] = {0.f,0.f,0.f,0.f,0.f,0.f,0.f,0.f};
        const ushort* Sb = St + (size_t)bh * NC * 8192 + hb * 4096 + 16 * tid;
        for (int cc = 0; cc < c; ++cc) {
            bf16x8 v0 = *(const bf16x8*)(Sb + (size_t)cc * 8192);
            bf16x8 v1 = *(const bf16x8*)(Sb + (size_t)cc * 8192 + 8);
            #pragma unroll
            for (int j = 0; j < 8; ++j) { a0[j] += bf2f(v0[j]); a1[j] += bf2f(v1[j]); }
        }
        const int r = tid >> 3, cb = (16 * tid) & 127;
        bf16x8 w0, w1;
        #pragma unroll
        for (int j = 0; j < 8; ++j) { w0[j] = f2bf(a0[j]); w1[j] = f2bf(a1[j]); }
        *(bf16x8*)(sSx + SWZ128(r, cb))     = w0;
        *(bf16x8*)(sSx + SWZ128(r, cb + 8)) = w1;
    }
    // z_excl lookback
    if (tid < 128) {
        float s = 0.f;
        const float* zp = z + bh * NC * M + tid;
        for (int cc = 0; cc < c; ++cc) s += zp[cc * M];
        sZ[tid] = s;
    }
    __syncthreads();  // B1: sPQ*, sPK*, sV, sSx, sZ staged

    // C: Amat[n][j] = phiQ^T . phiK (masked), row-sums -> intra norm
    f32x4 accO[2], accC[4];
    accO[0] = (f32x4){0.f,0.f,0.f,0.f}; accO[1] = (f32x4){0.f,0.f,0.f,0.f};
    for (int t = 0; t < 4; ++t) accC[t] = (f32x4){0.f,0.f,0.f,0.f};
    for (int mt = 0; mt < 4; ++mt) {
        const short* qh = (mt < 2) ? sPQ0 : sPQ1;
        const short* kh = (mt < 2) ? sPK0 : sPK1;
        const int cb = 32 * (mt & 1) + 8 * quad;
        bf16x8 aP = *(const bf16x8*)(qh + SWZ64(16 * wid + l16, cb));
        for (int jt = 0; jt < 4; ++jt) {
            bf16x8 bK2 = *(const bf16x8*)(kh + SWZ64(16 * jt + l16, cb));
            accC[jt] = MFMA16(aP, bK2, accC[jt]);
        }
    }
    float rsum[4] = {0.f, 0.f, 0.f, 0.f};
    for (int jt = 0; jt < 4; ++jt)
        for (int r = 0; r < 4; ++r) {
            const int n = 16 * wid + 4 * quad + r;
            const int j = 16 * jt + l16;
            const float av = (j <= n) ? accC[jt][r] : 0.f;
            rsum[r] += av;
            sAm[SWZ64(n, j)] = f2bf(av);
        }
    for (int r = 0; r < 4; ++r) {
        float s = rsum[r];
        s += __shfl_xor(s, 1); s += __shfl_xor(s, 2);
        s += __shfl_xor(s, 4); s += __shfl_xor(s, 8);
        if (l16 == 0) sNm[16 * wid + 4 * quad + r] = s;  // intra part of norm
    }
    // inter: accO += phiQ^T . S_excl (B-frags from sSx)
    for (int mt = 0; mt < 4; ++mt) {
        const short* qh = (mt < 2) ? sPQ0 : sPQ1;
        const int cb = 32 * (mt & 1) + 8 * quad;
        bf16x8 aP = *(const bf16x8*)(qh + SWZ64(16 * wid + l16, cb));
        for (int vt = 0; vt < 2; ++vt) {
            bf16x8 bS = *(const bf16x8*)(sSx + SWZ128(16 * vt + l16, 32 * mt + 8 * quad));
            accO[vt] = MFMA16(aP, bS, accO[vt]);
        }
    }
    // norm inter part, wave-parallel
    {
        const int n = tid & 63, g = tid >> 6;
        const short* qh = (g < 2) ? sPQ0 : sPQ1;
        float s = 0.f;
        for (int mm = 0; mm < 32; ++mm) {
            const int m = 32 * g + ((mm + n) & 31);      // rotate: spread banks
            s += bf2f(qh[SWZ64(n, m & 63)]) * sZ[m];
        }
        sNmP[n * 4 + g] = s;
    }
    __syncthreads();  // B2: sAm, sNm(intra), sNmP ready; sPQ/sPK/sSx now dead

    for (int jh = 0; jh < 2; ++jh) {   // E: accO += Amat . V-half
        bf16x8 aA = *(const bf16x8*)(sAm + SWZ64(16 * wid + l16, 32 * jh + 8 * quad));
        for (int vt = 0; vt < 2; ++vt) {
            bf16x8 bV = *(const bf16x8*)(sV + SWZ64(16 * vt + l16, 32 * jh + 8 * quad));
            accO[vt] = MFMA16(aA, bV, accO[vt]);
        }
    }
    if (tid < 64)
        sNm[tid] += sNmP[tid * 4] + sNmP[tid * 4 + 1] + sNmP[tid * 4 + 2] + sNmP[tid * 4 + 3];
    __syncthreads();  // B3: sNm final; sOut alias (@0) safe

    for (int vt = 0; vt < 2; ++vt)
        for (int r = 0; r < 4; ++r) {
            const int n = 16 * wid + 4 * quad + r, vl = 16 * vt + l16;
            sOut[n * 33 + vl] = accO[vt][r] / sNm[n];
        }
    __syncthreads();  // B4
    for (int i = tid; i < 2048; i += 256) {
        const int vl = i >> 6, n = i & 63;
        out[(bh * DV + hb * 32 + vl) * NSEQ + n0 + n] = sOut[n * 33 + vl];
    }
}

extern "C" void kernel_launch(void* const* d_in, const int* in_sizes, int n_in,
                              void* d_out, int out_size, void* d_ws, size_t ws_size,
                              hipStream_t stream)
{
    (void)in_sizes; (void)n_in; (void)out_size; (void)ws_size;
    const float* keys     = (const float*)d_in[0];
    const float* values   = (const float*)d_in[1];
    const float* queries  = (const float*)d_in[2];
    const float* features = (const float*)d_in[3];
    float* outp = (float*)d_out;

    // ws: St bf16 (4MB) | z f32 (128KB) | pQ images (4MB) | pK images (4MB)
    char* w = (char*)d_ws;
    const size_t MB = 1024 * 1024;
    ushort* St  = (ushort*)w;
    float*  z   = (float*)(w + 4 * MB);
    ushort* pQg = (ushort*)(w + 4 * MB + 128 * 1024);
    ushort* pKg = (ushort*)(w + 8 * MB + 128 * 1024);

    favor_p1<<<dim3(512), dim3(256), 0, stream>>>(keys, values, queries, features,
                                                  St, z, pQg, pKg);
    favor_p2k<<<dim3(512), dim3(256), 0, stream>>>(values, St, z, pQg, pKg, outp);
}

// Round 10
// 88.326 us; speedup vs baseline: 2.2521x; 1.0792x over previous
//
#include <hip/hip_runtime.h>

// FAVOR+ causal linear attention — 3-dispatch chunk-parallel pipeline,
// 2 blocks/CU (512-block grids), K3 images staged via global_load_lds(16).
// BH=8, D=DV=64, N=2048, M=128, chunk C=64, NC=32.
//
// K1 (per chunk, m-half mh): phi-gen (3 orientations), chunk-local S^T
//   column-half + z half + swizzled phi image halves -> global.
// K2: balanced parallel exclusive prefix scan (columns half-split 16+16,
//   carry via LDS) over St (bf16) and z (f32).
// K3 (per chunk, v-half vh): phi images -> LDS via global_load_lds width=16
//   (no VGPR round-trip; linear dest = K1's [row][half][8x16B] format),
//   S_excl B-frags hoisted to regs from scanned St, intra GEMM + inter GEMM
//   + norm + store.
// Measured ledger: fused+gridsync 71us in-kernel (R2), flags 83-144 (R6/R8),
// 2-dispatch lookback 95-99 (R3/R9) — all worse than this 3-dispatch shape.

#define BH 8
#define D 64
#define DV 64
#define NSEQ 2048
#define M 128
#define CHK 64
#define NC (NSEQ / CHK)
#define PHI_SCALE 0.08838834764831845f  // 1/sqrt(128)

typedef unsigned int uint;
typedef unsigned short ushort;
typedef __attribute__((ext_vector_type(8))) short bf16x8;
typedef __attribute__((ext_vector_type(4))) short bf16x4;
typedef __attribute__((ext_vector_type(4))) float f32x4;
typedef __attribute__((address_space(1))) const uint gu32;
typedef __attribute__((address_space(3))) uint lu32;
#define MFMA16(a, b, c) __builtin_amdgcn_mfma_f32_16x16x32_bf16((a), (b), (c), 0, 0, 0)

__device__ __forceinline__ short f2bf(float x) {  // RNE truncate fp32->bf16
    uint u = __float_as_uint(x);
    u += 0x7fffu + ((u >> 16) & 1u);
    return (short)(u >> 16);
}
__device__ __forceinline__ float bf2f(short b) {
    return __uint_as_float(((uint)(ushort)b) << 16);
}

// element-index XOR swizzles
#define SWZ64(r, c)  ((r) * 64  + ((c) ^ (((r) & 7) << 3)))
// combined [64][128] tile in K1's linear image order: per-half swizzle
#define SWZH(r, c)   ((r) * 128 + ((c) & 64) + (((c) & 63) ^ (((r) & 7) << 3)))

// ---------------- Kernel 1: 512 blocks = (m-half, chunk) ----------------
__global__ __launch_bounds__(256, 2) void favor_p1(
    const float* __restrict__ keys, const float* __restrict__ values,
    const float* __restrict__ queries, const float* __restrict__ features,
    ushort* __restrict__ St, float* __restrict__ z,
    ushort* __restrict__ pQg, ushort* __restrict__ pKg)
{
    const int mh = blockIdx.x >> 8, cid = blockIdx.x & 255;   // halves 256 apart
    const int bh = cid >> 5, c = cid & 31, n0 = c * CHK;
    const int tid = threadIdx.x;
    const int lane = tid & 63, wid = tid >> 6, quad = lane >> 4, l16 = lane & 15;

    __shared__ ulong2 smv[2048];               // 32 KB -> 2 blocks/CU
    short* sF    = (short*)smv;                // [64][64] bf16 F (this m-half)
    short* sPKmn = (short*)smv + 4096;         // [64][64] bf16 phiK[m_loc][n]
    short* sPQt  = (short*)smv + 8192;         // [64][64] bf16 phiQ^T cols m-half
    short* sPKt  = (short*)smv + 12288;        // [64][64] bf16 phiK^T cols m-half

    // F half-stage first (feeds the first barrier), then K/Q/V reg loads
    for (int k = 0; k < 4; ++k) {
        const int i = tid + 256 * k;           // float4 idx within half (1024)
        float4 f = ((const float4*)features)[mh * 1024 + i];
        const int e = 4 * i, row = e >> 6, col = e & 63;
        bf16x4 bq;
        bq[0] = f2bf(f.x); bq[1] = f2bf(f.y); bq[2] = f2bf(f.z); bq[3] = f2bf(f.w);
        *(bf16x4*)(sF + SWZ64(row, col)) = bq;
    }
    const float* Kb = keys    + bh * D * NSEQ + n0 + 16 * wid + l16;
    const float* Qb = queries + bh * D * NSEQ + n0 + 16 * wid + l16;
    bf16x8 bK[2], aQ[2], aV[2];
    for (int h = 0; h < 2; ++h)
        for (int j = 0; j < 8; ++j) {
            const int d = 32 * h + 8 * quad + j;
            bK[h][j] = f2bf(Kb[d * NSEQ]);     // B-frag phiK[m][n], A-frag phiK^T
            aQ[h][j] = f2bf(Qb[d * NSEQ]);     // A-frag phiQ^T
        }
    {
        const float* Vb = values + bh * DV * NSEQ + n0;
        for (int h = 0; h < 2; ++h) {
            const float4* vp = (const float4*)(Vb + (16 * wid + l16) * NSEQ + 32 * h + 8 * quad);
            float4 v0 = vp[0], v1 = vp[1];
            aV[h][0] = f2bf(v0.x); aV[h][1] = f2bf(v0.y);
            aV[h][2] = f2bf(v0.z); aV[h][3] = f2bf(v0.w);
            aV[h][4] = f2bf(v1.x); aV[h][5] = f2bf(v1.y);
            aV[h][6] = f2bf(v1.z); aV[h][7] = f2bf(v1.w);
        }
    }
    __syncthreads();  // B1: sF ready

    // phi generation for this m-half: one sF read feeds 3 MFMAs
    for (int mt = 0; mt < 4; ++mt) {
        f32x4 aMN = {0.f,0.f,0.f,0.f}, aQm = {0.f,0.f,0.f,0.f}, aKm = {0.f,0.f,0.f,0.f};
        for (int h = 0; h < 2; ++h) {
            bf16x8 fF = *(const bf16x8*)(sF + SWZ64(16 * mt + l16, 32 * h + 8 * quad));
            aMN = MFMA16(fF, bK[h], aMN);      // D[m][n] = F . K
            aQm = MFMA16(aQ[h], fF, aQm);      // D[n][m] = Q^T . F^T
            aKm = MFMA16(bK[h], fF, aKm);      // D[n][m] = K^T . F^T
        }
        for (int r = 0; r < 4; ++r) {
            const int mr = 16 * mt + 4 * quad + r;     // local m row
            sPKmn[SWZ64(mr, 16 * wid + l16)] = f2bf(fmaxf(aMN[r], 0.f) * PHI_SCALE);
            const int nr = 16 * wid + 4 * quad + r;    // row n
            sPQt[SWZ64(nr, 16 * mt + l16)] = f2bf(fmaxf(aQm[r], 0.f) * PHI_SCALE);
            sPKt[SWZ64(nr, 16 * mt + l16)] = f2bf(fmaxf(aKm[r], 0.f) * PHI_SCALE);
        }
    }
    __syncthreads();  // B2: phi tiles ready

    // z half (wave 0 only; waves 1-3 proceed to St MFMAs)
    if (tid < 64) {
        float s = 0.f;
        for (int n = 0; n < 64; ++n) s += bf2f(sPKmn[SWZ64(tid, (n + tid) & 63)]);
        z[(bh * NC + c) * M + mh * 64 + tid] = s;
    }

    // S^T[v][m-half] chunk-local -> global St
    {
        ushort* So = St + (size_t)(bh * NC + c) * (DV * M);
        for (int mt = 0; mt < 4; ++mt) {
            f32x4 acc = {0.f,0.f,0.f,0.f};
            for (int h = 0; h < 2; ++h) {
                bf16x8 bP = *(const bf16x8*)(sPKmn + SWZ64(16 * mt + l16, 32 * h + 8 * quad));
                acc = MFMA16(aV[h], bP, acc);
            }
            for (int r = 0; r < 4; ++r)
                So[(16 * wid + 4 * quad + r) * M + mh * 64 + 16 * mt + l16] =
                    (ushort)f2bf(acc[r]);
        }
    }

    // phi image halves -> global ([row][half][8 x ulong2] format, coalesced)
    {
        ushort* pQc = pQg + (size_t)(bh * NC + c) * 8192;
        ushort* pKc = pKg + (size_t)(bh * NC + c) * 8192;
        const ulong2* sq = (const ulong2*)sPQt;
        const ulong2* sk = (const ulong2*)sPKt;
        for (int i = tid; i < 512; i += 256) {
            const int row = i >> 3, q = i & 7;
            ((ulong2*)pQc)[row * 16 + mh * 8 + q] = sq[i];
            ((ulong2*)pKc)[row * 16 + mh * 8 + q] = sk[i];
        }
    }
}

// ---------------- Kernel 2: exclusive prefix scans over chunks ----------------
// St: 512 blocks x 128 columns; each column split across 2 thread-halves
// (16 chunks each), carry via LDS -> same bitwise order, 2 blocks/CU.
__global__ __launch_bounds__(256, 2) void favor_p2(ushort* __restrict__ St,
                                                   float* __restrict__ z)
{
    __shared__ float carry[128];
    const int tid = threadIdx.x;
    if (blockIdx.x < 512) {
        const int col = blockIdx.x * 128 + (tid & 127);   // 0..65535
        const int half = tid >> 7;                        // wave-uniform
        const int bh = col >> 13, vm = col & 8191;
        ushort* p = St + (size_t)bh * NC * 8192 + vm;
        float vals[16];
        #pragma unroll
        for (int k = 0; k < 16; ++k) vals[k] = bf2f(p[(16 * half + k) * 8192]);
        if (half == 0) {
            float total = 0.f;
            #pragma unroll
            for (int k = 0; k < 16; ++k) total += vals[k];
            carry[tid] = total;
        }
        __syncthreads();
        float run = (half == 0) ? 0.f : carry[tid & 127];
        #pragma unroll
        for (int k = 0; k < 16; ++k) {
            p[(16 * half + k) * 8192] = (ushort)f2bf(run);
            run += vals[k];
        }
    } else {                                              // z: 4 blocks, 1024 cols
        const int i = (blockIdx.x - 512) * 256 + tid;
        const int bh = i >> 7, m = i & 127;
        float* p = z + bh * NC * M + m;
        float vals[NC];
        #pragma unroll
        for (int cc = 0; cc < NC; ++cc) vals[cc] = p[cc * M];
        float run = 0.f;
        #pragma unroll
        for (int cc = 0; cc < NC; ++cc) { p[cc * M] = run; run += vals[cc]; }
    }
}

// ---------------- Kernel 3: 512 blocks = (v-half, chunk) ----------------
__global__ __launch_bounds__(256, 2) void favor_p3(
    const float* __restrict__ values, const ushort* __restrict__ St,
    const float* __restrict__ z, const ushort* __restrict__ pQg,
    const ushort* __restrict__ pKg, float* __restrict__ out)
{
    const int vh = blockIdx.x >> 8, cid = blockIdx.x & 255;
    const int bh = cid >> 5, c = cid & 31, n0 = c * CHK;
    const int tid = threadIdx.x;
    const int lane = tid & 63, wid = tid >> 6, quad = lane >> 4, l16 = lane & 15;

    __shared__ ulong2 smv[2928];                    // 46848 B -> 2 blocks/CU
    char* sm = (char*)smv;
    short* sPQt = (short*)sm;                       // @0     [64][128] phiQ^T (SWZH)
    short* sPKt = (short*)(sm + 16384);             // @16384 [64][128] phiK^T (SWZH)
    short* sV   = (short*)(sm + 32768);             // @32768 [32][64]  V half SWZ64
    short* sAm  = (short*)(sm + 36864);             // @36864 [64][64]  Amat  SWZ64
    float* sNm  = (float*)(sm + 45056);             // [64] norm
    float* sNmP = (float*)(sm + 45312);             // [64][4] norm-inter partials
    float* sZ   = (float*)(sm + 46336);             // [128] z_excl
    float* sOut = (float*)sm;                       // [64][33] f32 8448B (aliases
                                                    //  sPQt; all reads pre-B2)

    // hoist S_excl B-frags into registers (latency hides under staging)
    const ushort* Sb = St + (size_t)(bh * NC + c) * (DV * M);
    bf16x8 bS[4][2];
    #pragma unroll
    for (int mt = 0; mt < 4; ++mt)
        #pragma unroll
        for (int vt = 0; vt < 2; ++vt)
            bS[mt][vt] = *(const bf16x8*)(Sb + (vh * 32 + 16 * vt + l16) * M
                                             + 32 * mt + 8 * quad);

    // phi images global->LDS via global_load_lds width=16: linear dest equals
    // K1's [row][half][8x16B] order; each wave-call moves 1KB (64 lanes x 16B)
    {
        const char* gQ = (const char*)(pQg + (size_t)(bh * NC + c) * 8192);
        const char* gK = (const char*)(pKg + (size_t)(bh * NC + c) * 8192);
        for (int k = 0; k < 4; ++k) {
            const int off = (4 * k + wid) * 1024;   // wave-uniform LDS/global base
            __builtin_amdgcn_global_load_lds(
                (gu32*)(gQ + off + lane * 16), (lu32*)((char*)sPQt + off), 16, 0, 0);
            __builtin_amdgcn_global_load_lds(
                (gu32*)(gK + off + lane * 16), (lu32*)((char*)sPKt + off), 16, 0, 0);
        }
    }
    // V half-stage: thread -> row tid>>3 (32 rows), 8 cols
    {
        const int vrow = tid >> 3, cb = (tid & 7) * 8;
        const float4* vp = (const float4*)(values + (bh * DV + vh * 32 + vrow) * NSEQ
                                                  + n0 + cb);
        float4 f0 = vp[0], f1 = vp[1];
        bf16x8 w;
        w[0] = f2bf(f0.x); w[1] = f2bf(f0.y); w[2] = f2bf(f0.z); w[3] = f2bf(f0.w);
        w[4] = f2bf(f1.x); w[5] = f2bf(f1.y); w[6] = f2bf(f1.z); w[7] = f2bf(f1.w);
        *(bf16x8*)(sV + SWZ64(vrow, cb)) = w;
    }
    if (tid < 128) sZ[tid] = z[(bh * NC + c) * M + tid];   // already exclusive
    __syncthreads();  // B1: vmcnt drained -> sPQt, sPKt, sV, sZ staged

    // C: Amat[n][j] = phiQ^T . phiK (masked), row-sums -> intra norm (dup/half)
    f32x4 accO[2], accC[4];
    accO[0] = (f32x4){0.f,0.f,0.f,0.f}; accO[1] = (f32x4){0.f,0.f,0.f,0.f};
    for (int t = 0; t < 4; ++t) accC[t] = (f32x4){0.f,0.f,0.f,0.f};
    for (int mt = 0; mt < 4; ++mt) {
        bf16x8 aP = *(const bf16x8*)(sPQt + SWZH(16 * wid + l16, 32 * mt + 8 * quad));
        for (int jt = 0; jt < 4; ++jt) {
            bf16x8 bK2 = *(const bf16x8*)(sPKt + SWZH(16 * jt + l16, 32 * mt + 8 * quad));
            accC[jt] = MFMA16(aP, bK2, accC[jt]);
        }
    }
    float rsum[4] = {0.f, 0.f, 0.f, 0.f};
    for (int jt = 0; jt < 4; ++jt)
        for (int r = 0; r < 4; ++r) {
            const int n = 16 * wid + 4 * quad + r;
            const int j = 16 * jt + l16;
            const float av = (j <= n) ? accC[jt][r] : 0.f;
            rsum[r] += av;
            sAm[SWZ64(n, j)] = f2bf(av);
        }
    for (int r = 0; r < 4; ++r) {
        float s = rsum[r];
        s += __shfl_xor(s, 1); s += __shfl_xor(s, 2);
        s += __shfl_xor(s, 4); s += __shfl_xor(s, 8);
        if (l16 == 0) sNm[16 * wid + 4 * quad + r] = s;  // intra part of norm
    }

    // inter: accO += phiQ^T . S_excl (B-frags already in registers)
    for (int mt = 0; mt < 4; ++mt) {
        bf16x8 aP = *(const bf16x8*)(sPQt + SWZH(16 * wid + l16, 32 * mt + 8 * quad));
        for (int vt = 0; vt < 2; ++vt)
            accO[vt] = MFMA16(aP, bS[mt][vt], accO[vt]);
    }
    // norm inter part, wave-parallel: thread (n=tid&63, g=tid>>6) sums 32 m's
    {
        const int n = tid & 63, g = tid >> 6;
        float s = 0.f;
        for (int mm = 0; mm < 32; ++mm) {
            const int m = 32 * g + ((mm + n) & 31);      // rotate: spread banks
            s += bf2f(sPQt[SWZH(n, m)]) * sZ[m];
        }
        sNmP[n * 4 + g] = s;
    }
    __syncthreads();  // B2: sAm, sNm(intra), sNmP ready; sPQt/sPKt now dead

    // E: accO += Amat . V-half  (intra-chunk causal)
    for (int jh = 0; jh < 2; ++jh) {
        bf16x8 aA = *(const bf16x8*)(sAm + SWZ64(16 * wid + l16, 32 * jh + 8 * quad));
        for (int vt = 0; vt < 2; ++vt) {
            bf16x8 bV = *(const bf16x8*)(sV + SWZ64(16 * vt + l16, 32 * jh + 8 * quad));
            accO[vt] = MFMA16(aA, bV, accO[vt]);
        }
    }
    if (tid < 64)
        sNm[tid] += sNmP[tid * 4] + sNmP[tid * 4 + 1] + sNmP[tid * 4 + 2] + sNmP[tid * 4 + 3];
    __syncthreads();  // B3: sNm final; pre-B2 sPQt reads done -> sOut alias safe

    for (int vt = 0; vt < 2; ++vt)
        for (int r = 0; r < 4; ++r) {
            const int n = 16 * wid + 4 * quad + r, vl = 16 * vt + l16;
            sOut[n * 33 + vl] = accO[vt][r] / sNm[n];
        }
    __syncthreads();  // B4
    for (int i = tid; i < 2048; i += 256) {
        const int vl = i >> 6, n = i & 63;
        out[(bh * DV + vh * 32 + vl) * NSEQ + n0 + n] = sOut[n * 33 + vl];
    }
}

extern "C" void kernel_launch(void* const* d_in, const int* in_sizes, int n_in,
                              void* d_out, int out_size, void* d_ws, size_t ws_size,
                              hipStream_t stream)
{
    (void)in_sizes; (void)n_in; (void)out_size; (void)ws_size;
    const float* keys     = (const float*)d_in[0];
    const float* values   = (const float*)d_in[1];
    const float* queries  = (const float*)d_in[2];
    const float* features = (const float*)d_in[3];
    float* outp = (float*)d_out;

    // ws: St bf16 (4MB) | z f32 (128KB) | pQ images (4MB) | pK images (4MB)
    char* w = (char*)d_ws;
    const size_t MB = 1024 * 1024;
    ushort* St  = (ushort*)w;
    float*  z   = (float*)(w + 4 * MB);
    ushort* pQg = (ushort*)(w + 4 * MB + 128 * 1024);
    ushort* pKg = (ushort*)(w + 8 * MB + 128 * 1024);

    favor_p1<<<dim3(512), dim3(256), 0, stream>>>(keys, values, queries, features,
                                                  St, z, pQg, pKg);
    favor_p2<<<dim3(516), dim3(256), 0, stream>>>(St, z);
    favor_p3<<<dim3(512), dim3(256), 0, stream>>>(values, St, z, pQg, pKg, outp);
}